// Round 1
// baseline (622.210 us; speedup 1.0000x reference)
//
#include <hip/hip_runtime.h>

// BATCH=131072, FEAT=512, NUM_CLASS=8192.
// Single-kernel, d_ws-FREE segment-sum:
//   256 blocks = 128 float4-feature-slices x 2 class-halves.
//   Each block owns slice s (16B of every row) and classes [h*4096,(h+1)*4096),
//   accumulating into a 64 KB LDS array with ds_add_f32 atomics, then writes
//   out[c][s] = class_sums[c][s] + acc[c] once. No workspace, no global atomics
//   on the hot path, no second pass.
// Slice mapping s = (b&15)*8 + (b>>4): the 8 blocks sharing each 128B input
// line satisfy b % 8 == const -> same XCD under round-robin dispatch -> each
// HBM line fetched once, consumed 8x from that XCD's private L2.

#define FEAT   512
#define FEAT4  128           // float4s per row
#define NCLS_MAX 8192
#define CSPAN  4096          // classes per block (half split); 64 KB LDS
#define TPB    1024

typedef float f4 __attribute__((ext_vector_type(4)));

__global__ __launch_bounds__(TPB) void k_seg(const f4* __restrict__ batch,
                                             const f4* __restrict__ csums,
                                             const int4* __restrict__ t4,
                                             const int* __restrict__ targets,
                                             f4* __restrict__ out,
                                             int batch_n, int num_class) {
    const int bb = blockIdx.x & 127;          // slice index space
    const int h  = blockIdx.x >> 7;           // class half
    const int s  = ((bb & 15) << 3) | (bb >> 4);   // XCD-aligned slice
    const int cbase = h * CSPAN;
    const int cspan = min(CSPAN, num_class - cbase);
    if (cspan <= 0) return;                   // uniform per block: safe

    // feature-major accumulator: bank(&acc[f][c]) = c % 32
    __shared__ float acc[4][CSPAN];

    f4* accv = (f4*)acc;                      // 4096 float4s
    for (int i = threadIdx.x; i < CSPAN; i += TPB) accv[i] = (f4){0.f, 0.f, 0.f, 0.f};
    __syncthreads();

    const int n4 = batch_n >> 2;
    for (int i = threadIdx.x; i < n4; i += TPB) {
        int4 t = t4[i];                       // 4 consecutive row labels
        size_t r = (size_t)i << 2;
        int c0 = t.x - cbase, c1 = t.y - cbase, c2 = t.z - cbase, c3 = t.w - cbase;
        if ((unsigned)c0 < (unsigned)cspan) {
            f4 v = batch[(r + 0) * FEAT4 + s];
            atomicAdd(&acc[0][c0], v.x); atomicAdd(&acc[1][c0], v.y);
            atomicAdd(&acc[2][c0], v.z); atomicAdd(&acc[3][c0], v.w);
        }
        if ((unsigned)c1 < (unsigned)cspan) {
            f4 v = batch[(r + 1) * FEAT4 + s];
            atomicAdd(&acc[0][c1], v.x); atomicAdd(&acc[1][c1], v.y);
            atomicAdd(&acc[2][c1], v.z); atomicAdd(&acc[3][c1], v.w);
        }
        if ((unsigned)c2 < (unsigned)cspan) {
            f4 v = batch[(r + 2) * FEAT4 + s];
            atomicAdd(&acc[0][c2], v.x); atomicAdd(&acc[1][c2], v.y);
            atomicAdd(&acc[2][c2], v.z); atomicAdd(&acc[3][c2], v.w);
        }
        if ((unsigned)c3 < (unsigned)cspan) {
            f4 v = batch[(r + 3) * FEAT4 + s];
            atomicAdd(&acc[0][c3], v.x); atomicAdd(&acc[1][c3], v.y);
            atomicAdd(&acc[2][c3], v.z); atomicAdd(&acc[3][c3], v.w);
        }
    }
    // tail rows (batch not multiple of 4) — never taken for BATCH=131072
    if (threadIdx.x < (batch_n & 3)) {
        int k = (n4 << 2) + threadIdx.x;
        int c = targets[k] - cbase;
        if ((unsigned)c < (unsigned)cspan) {
            f4 v = batch[(size_t)k * FEAT4 + s];
            atomicAdd(&acc[0][c], v.x); atomicAdd(&acc[1][c], v.y);
            atomicAdd(&acc[2][c], v.z); atomicAdd(&acc[3][c], v.w);
        }
    }
    __syncthreads();

    // epilogue: out = class_sums + acc (each out element written exactly once)
    for (int c = threadIdx.x; c < cspan; c += TPB) {
        f4 v;
        v.x = acc[0][c]; v.y = acc[1][c]; v.z = acc[2][c]; v.w = acc[3][c];
        size_t o = (size_t)(cbase + c) * FEAT4 + s;
        v += csums[o];
        out[o] = v;
    }
}

// ---------- fallback (unexpected shapes): copy + global atomic scatter ----------
__global__ void k_copy(const float4* __restrict__ src, float4* __restrict__ dst, int n4) {
    int i = blockIdx.x * blockDim.x + threadIdx.x;
    if (i < n4) dst[i] = src[i];
}

__global__ __launch_bounds__(128) void k_atomic(const float4* __restrict__ batch,
                                                const int* __restrict__ targets,
                                                float* __restrict__ out, int batch_n) {
    const int r = blockIdx.x;
    const int t = threadIdx.x;
    if (r >= batch_n) return;
    float4 v = batch[(size_t)r * FEAT4 + t];
    float* o = out + (size_t)targets[r] * FEAT + t * 4;
    atomicAdd(o + 0, v.x);
    atomicAdd(o + 1, v.y);
    atomicAdd(o + 2, v.z);
    atomicAdd(o + 3, v.w);
}

extern "C" void kernel_launch(void* const* d_in, const int* in_sizes, int n_in,
                              void* d_out, int out_size, void* d_ws, size_t ws_size,
                              hipStream_t stream) {
    const float* batch_samples = (const float*)d_in[0];
    const float* class_sums    = (const float*)d_in[1];
    const int*   targets       = (const int*)d_in[2];
    // d_in[3] (idx) unused in forward math.

    const int batch     = in_sizes[2];          // 131072
    const int num_class = out_size / FEAT;      // 8192
    float* out = (float*)d_out;

    (void)d_ws; (void)ws_size;                  // deliberately unused: ws-free

    const int feat = (batch > 0) ? in_sizes[0] / batch : 0;

    if (num_class >= 1 && num_class <= NCLS_MAX && feat == FEAT) {
        k_seg<<<256, TPB, 0, stream>>>((const f4*)batch_samples,
                                       (const f4*)class_sums,
                                       (const int4*)targets, targets,
                                       (f4*)out, batch, num_class);
    } else {
        const int nv4 = out_size / 4;
        k_copy<<<(nv4 + 255) / 256, 256, 0, stream>>>((const float4*)class_sums,
                                                      (float4*)out, nv4);
        k_atomic<<<batch, 128, 0, stream>>>((const float4*)batch_samples,
                                            targets, out, batch);
    }
}

// Round 2
// 374.816 us; speedup vs baseline: 1.6600x; 1.6600x over previous
//
#include <hip/hip_runtime.h>

// BATCH=131072, FEAT=512, NUM_CLASS=8192.
// Pipeline (3 graph nodes): memset(fill+ovf_cnt) -> bucket-scatter
// (rows_buf[c*CAP+pos]) -> per-class gather-sum (nontemporal float4) with the
// overflow fixup MERGED into the sum kernel (ovf_cnt==0 in practice; the scan
// degenerates to one cached scalar load per block, saving the k_ovf launch).
//
// Round-1 lesson (measured): LDS ds_add_f32 with random addresses costs ~3.3
// cycles per lane-atomic -> 357 us. The gather formulation reads each batch
// row exactly once, coalesced, no atomics on the hot path: chain ~55 us vs
// ~46 us pure-BW floor. The other ~322 us of the timed window is the
// harness's unconditional 2x1GiB ws re-poison running at 83% of HBM peak.

#define FEAT 512
#define FEAT4 128           // FEAT/4 float4s per row
#define CAP   128           // bucket capacity per class (Poisson(16) -> never hit)

typedef float f4 __attribute__((ext_vector_type(4)));   // clang-native vec4

__device__ __forceinline__ void bucket_one(int c, int row, int* __restrict__ fill,
                                           int* __restrict__ rows_buf,
                                           int* __restrict__ ovf_cnt,
                                           int* __restrict__ ovf) {
    int pos = atomicAdd(&fill[c], 1);
    if (pos < CAP) rows_buf[c * CAP + pos] = row;
    else           ovf[atomicAdd(ovf_cnt, 1)] = row;
}

__global__ __launch_bounds__(256) void k_scatter(const int4* __restrict__ t4,
                                                 int* __restrict__ fill,
                                                 int* __restrict__ rows_buf,
                                                 int* __restrict__ ovf_cnt,
                                                 int* __restrict__ ovf, int n4,
                                                 const int* __restrict__ targets,
                                                 int batch) {
    int i = blockIdx.x * blockDim.x + threadIdx.x;
    if (i < n4) {
        int4 v = t4[i];
        int r = i * 4;
        bucket_one(v.x, r + 0, fill, rows_buf, ovf_cnt, ovf);
        bucket_one(v.y, r + 1, fill, rows_buf, ovf_cnt, ovf);
        bucket_one(v.z, r + 2, fill, rows_buf, ovf_cnt, ovf);
        bucket_one(v.w, r + 3, fill, rows_buf, ovf_cnt, ovf);
    }
    if (i == 0) {                        // tail (batch not multiple of 4)
        for (int k = n4 * 4; k < batch; ++k)
            bucket_one(targets[k], k, fill, rows_buf, ovf_cnt, ovf);
    }
}

// One block (128 threads) per class; each thread owns one float4 column.
// n <= CAP rows via rows_buf; overflow rows (never in practice) found by
// scanning the ovf list for targets[row]==c.
__global__ __launch_bounds__(128) void k_sum(const f4* __restrict__ batch,
                                             const f4* __restrict__ csums,
                                             const int* __restrict__ fill,
                                             const int* __restrict__ rows_buf,
                                             const int* __restrict__ ovf_cnt,
                                             const int* __restrict__ ovf,
                                             const int* __restrict__ targets,
                                             f4* __restrict__ out) {
    const int c = blockIdx.x;
    const int t = threadIdx.x;      // 0..127
    const int n = min(fill[c], CAP);

    __shared__ int sidx[CAP];
    if (t < n) sidx[t] = rows_buf[c * CAP + t];

    f4 acc = csums[(size_t)c * FEAT4 + t];   // independent of the barrier
    __syncthreads();

    int j = 0;
    for (; j + 8 <= n; j += 8) {
        f4 v0 = __builtin_nontemporal_load(&batch[(size_t)sidx[j + 0] * FEAT4 + t]);
        f4 v1 = __builtin_nontemporal_load(&batch[(size_t)sidx[j + 1] * FEAT4 + t]);
        f4 v2 = __builtin_nontemporal_load(&batch[(size_t)sidx[j + 2] * FEAT4 + t]);
        f4 v3 = __builtin_nontemporal_load(&batch[(size_t)sidx[j + 3] * FEAT4 + t]);
        f4 v4 = __builtin_nontemporal_load(&batch[(size_t)sidx[j + 4] * FEAT4 + t]);
        f4 v5 = __builtin_nontemporal_load(&batch[(size_t)sidx[j + 5] * FEAT4 + t]);
        f4 v6 = __builtin_nontemporal_load(&batch[(size_t)sidx[j + 6] * FEAT4 + t]);
        f4 v7 = __builtin_nontemporal_load(&batch[(size_t)sidx[j + 7] * FEAT4 + t]);
        acc += ((v0 + v1) + (v2 + v3)) + ((v4 + v5) + (v6 + v7));
    }
    for (; j < n; ++j)
        acc += __builtin_nontemporal_load(&batch[(size_t)sidx[j] * FEAT4 + t]);

    // Overflow fixup, merged: cnt==0 in practice -> one cached scalar load.
    const int cnt = *ovf_cnt;
    for (int e = 0; e < cnt; ++e) {
        int row = ovf[e];
        if (targets[row] == c)
            acc += batch[(size_t)row * FEAT4 + t];
    }

    __builtin_nontemporal_store(acc, &out[(size_t)c * FEAT4 + t]);
}

// ---------- fallback: plain atomic scatter-add (if ws too small) ----------
__global__ void k_copy(const float4* __restrict__ src, float4* __restrict__ dst, int n4) {
    int i = blockIdx.x * blockDim.x + threadIdx.x;
    if (i < n4) dst[i] = src[i];
}

__global__ __launch_bounds__(128) void k_atomic(const float4* __restrict__ batch,
                                                const int* __restrict__ targets,
                                                float* __restrict__ out, int batch_n) {
    const int r = blockIdx.x;
    const int t = threadIdx.x;
    if (r >= batch_n) return;
    float4 v = batch[(size_t)r * FEAT4 + t];
    float* o = out + (size_t)targets[r] * FEAT + t * 4;
    atomicAdd(o + 0, v.x);
    atomicAdd(o + 1, v.y);
    atomicAdd(o + 2, v.z);
    atomicAdd(o + 3, v.w);
}

extern "C" void kernel_launch(void* const* d_in, const int* in_sizes, int n_in,
                              void* d_out, int out_size, void* d_ws, size_t ws_size,
                              hipStream_t stream) {
    const float* batch_samples = (const float*)d_in[0];
    const float* class_sums    = (const float*)d_in[1];
    const int*   targets       = (const int*)d_in[2];
    // d_in[3] (idx) unused in forward math.

    const int batch     = in_sizes[2];          // 131072
    const int num_class = out_size / FEAT;      // 8192
    float* out = (float*)d_out;

    // ws layout (ints): fill[num_class] | ovf_cnt[1] | pad | rows_buf[num_class*CAP] | ovf[batch]
    const size_t rows_off = ((size_t)num_class + 64) & ~63ull;   // 256B-align
    const size_t ovf_off  = rows_off + (size_t)num_class * CAP;
    const size_t need     = (ovf_off + (size_t)batch) * 4;

    if (ws_size >= need) {
        int* fill     = (int*)d_ws;
        int* ovf_cnt  = fill + num_class;
        int* rows_buf = fill + rows_off;
        int* ovf      = fill + ovf_off;
        const int n4 = batch / 4;

        (void)hipMemsetAsync(fill, 0, ((size_t)num_class + 1) * 4, stream);
        k_scatter<<<(n4 + 255) / 256, 256, 0, stream>>>((const int4*)targets, fill,
                                                        rows_buf, ovf_cnt, ovf,
                                                        n4, targets, batch);
        k_sum<<<num_class, 128, 0, stream>>>((const f4*)batch_samples,
                                             (const f4*)class_sums,
                                             fill, rows_buf, ovf_cnt, ovf,
                                             targets, (f4*)out);
    } else {
        const int nv4 = out_size / 4;
        k_copy<<<(nv4 + 255) / 256, 256, 0, stream>>>((const float4*)class_sums,
                                                      (float4*)out, nv4);
        k_atomic<<<batch, 128, 0, stream>>>((const float4*)batch_samples,
                                            targets, out, batch);
    }
}